// Round 7
// baseline (277.740 us; speedup 1.0000x reference)
//
#include <hip/hip_runtime.h>
#include <hip/hip_cooperative_groups.h>
#include <stdint.h>
#include <math.h>

namespace cg = cooperative_groups;

#define NTOT (9*128*128)         // 147456
#define PRE_N 6000
#define POST_N 300
#define CAND_CAP 8192
#define NWORDS 94                // ceil(6000/64)
#define GRIDB 256                // 1 block/CU -> cooperative co-residency guaranteed
#define BT 256
#define GSIZE (GRIDB*BT)         // 65536
#define RTILE 4096               // rank LDS tile (32 KiB)

typedef unsigned long long u64;

// ---- ws layout (bytes) ----
constexpr size_t OFF_META = 0;                            // 64 B (meta[0]=cand counter)
constexpr size_t OFF_CAND = 64;                           // u64*CAND_CAP   = 65536
constexpr size_t OFF_CBOX = OFF_CAND + CAND_CAP*8;        // float4*CAND_CAP= 131072
constexpr size_t OFF_KEY2 = OFF_CBOX + CAND_CAP*16;       // u64*PRE_N      (pad 48128)
constexpr size_t OFF_BOXA = OFF_KEY2 + 48128;             // float4*PRE_N   (pad 96256)
constexpr size_t OFF_SP   = OFF_BOXA + 96256;             // float4*PRE_N
constexpr size_t OFF_SD   = OFF_SP + 96256;               // float4*PRE_N
constexpr size_t OFF_SUP  = OFF_SD + 96256;               // u64*PRE_N*NWORDS = 4512000

// monotone float -> uint (ascending order preserved, total order)
static __device__ __forceinline__ unsigned int ford(float f) {
    unsigned int b = __float_as_uint(f);
    return b ^ ((b & 0x80000000u) ? 0xFFFFFFFFu : 0x80000000u);
}

__global__ void __launch_bounds__(BT)
k_all(const float* __restrict__ scores,
      const float* __restrict__ deltas,
      const float* __restrict__ anchors,
      float4* __restrict__ out,
      u64* __restrict__ cand, float4* __restrict__ cbox,
      u64* __restrict__ key2, float4* __restrict__ boxA,
      float4* __restrict__ sP, float4* __restrict__ sD,
      u64* __restrict__ sup, unsigned int* __restrict__ meta)
{
    cg::grid_group grid = cg::this_grid();
    __shared__ u64 tile[RTILE];          // 32 KiB
    __shared__ int keepj[POST_N];
    __shared__ int s_kept;

    const int tid  = threadIdx.x;
    const int gtid = blockIdx.x * BT + tid;

    // P0: zero candidate counter (ws is poisoned 0xAA by harness)
    if (gtid == 0) meta[0] = 0;
    grid.sync();

    // P1: decode boxes, append valid candidates.
    // Only valid boxes can ever reach the output (invalid score = -inf, V=0
    // downstream). Append order is nondeterministic; ranks over the unique
    // keys make final placement deterministic.
    for (int i = gtid; i < NTOT; i += GSIZE) {
        int a   = i >> 14;
        int rem = i & 16383;
        float4 d  = ((const float4*)deltas)[a * 16384 + rem]; // raw-reshape layout
        float4 an = ((const float4*)anchors)[i];
        float x1 = fmaxf(an.x + d.x, 0.0f);
        float y1 = fmaxf(an.y + d.y, 0.0f);
        float bw = fmaxf(an.z + d.z, 0.0f);
        float bh = fmaxf(an.w + d.w, 0.0f);
        float x2 = fminf(x1 + bw - 1.0f, 127.0f);   // uses pre-clamp x1
        float y2 = fminf(y1 + bh - 1.0f, 127.0f);
        x1 = fminf(x1, 127.0f);
        y1 = fminf(y1, 127.0f);
        bw = x2 - x1 + 1.0f;
        bh = y2 - y1 + 1.0f;
        if ((bw >= 16.0f) && (bh >= 16.0f)) {
            unsigned int inv = ~ford(scores[i]);    // ascending inv <=> score desc
            u64 key = ((u64)inv << 32) | (unsigned int)i;
            unsigned int p = atomicAdd(&meta[0], 1u);
            if (p < CAND_CAP) { cand[p] = key; cbox[p] = make_float4(x1, y1, bw, bh); }
        }
    }
    grid.sync();

    unsigned int cnt = meta[0];
    if (cnt > CAND_CAP) cnt = CAND_CAP;
    unsigned int nreal = (cnt < PRE_N) ? cnt : PRE_N;
    int wreal = ((int)nreal + 63) >> 6;

    // P2: rank by score-key (exact, keys unique). rank = #{keys < mine}.
    // rank r < PRE_N -> top-k slot r (score desc, idx asc = lax.top_k order).
    if ((unsigned)(blockIdx.x * BT) < cnt) {      // block-uniform skip
        bool act = (gtid < (int)cnt);
        u64 my = act ? cand[gtid] : ~0ull;
        int r = 0;
        for (unsigned int base = 0; base < cnt; base += RTILE) {
            unsigned int n = min((unsigned int)RTILE, cnt - base);
            for (unsigned int t = tid; t < n; t += BT) tile[t] = cand[base + t];
            __syncthreads();
            if (act) {
                unsigned int t = 0;
                for (; t + 4 <= n; t += 4) {
                    r += (tile[t]   < my);
                    r += (tile[t+1] < my);
                    r += (tile[t+2] < my);
                    r += (tile[t+3] < my);
                }
                for (; t < n; ++t) r += (tile[t] < my);
            }
            __syncthreads();
        }
        if (act && r < PRE_N) {
            float4 b = cbox[gtid];
            float py2 = (b.y + b.w) - 1.0f;
            key2[r] = ((u64)(~ford(py2)) << 32) | (u64)r;  // (py2 desc, stable by rank)
            boxA[r] = b;
        }
    }
    grid.sync();

    // P3: rank by py2-key among top nreal; scatter into final NMS order.
    if ((unsigned)(blockIdx.x * BT) < nreal) {
        bool act = (gtid < (int)nreal);
        u64 my = act ? key2[gtid] : ~0ull;
        int r = 0;
        for (unsigned int base = 0; base < nreal; base += RTILE) {
            unsigned int n = min((unsigned int)RTILE, nreal - base);
            for (unsigned int t = tid; t < n; t += BT) tile[t] = key2[base + t];
            __syncthreads();
            if (act) {
                unsigned int t = 0;
                for (; t + 4 <= n; t += 4) {
                    r += (tile[t]   < my);
                    r += (tile[t+1] < my);
                    r += (tile[t+2] < my);
                    r += (tile[t+3] < my);
                }
                for (; t < n; ++t) r += (tile[t] < my);
            }
            __syncthreads();
        }
        if (act) {
            float4 b = boxA[gtid];
            sP[r] = b;
            sD[r] = make_float4((b.x + b.z) - 1.0f, (b.y + b.w) - 1.0f,
                                b.z * b.w, 1.0f);
        }
    }
    grid.sync();

    // P4: suppression bitmatrix (i suppresses j: i<j and IoU-test true)
    for (int t = gtid; t < (int)nreal * wreal; t += GSIZE) {
        int i = t % (int)nreal;
        int w = t / (int)nreal;
        float4 p  = sP[i];
        float4 dI = sD[i];
        u64 bits = 0;
        int jbase = w * 64;
        int jend  = min(jbase + 64, (int)nreal);
        for (int j = max(jbase, i + 1); j < jend; ++j) {
            float4 q  = sP[j];
            float4 dJ = sD[j];
            float iw = fmaxf(fminf(dI.x, dJ.x) - fmaxf(p.x, q.x) + 1.0f, 0.0f);
            float ih = fmaxf(fminf(dI.y, dJ.y) - fmaxf(p.y, q.y) + 1.0f, 0.0f);
            if (iw * ih >= 0.7f * dJ.z) bits |= 1ull << (j - jbase);
        }
        sup[(size_t)i * NWORDS + w] = bits;
    }
    grid.sync();

    // P5: greedy scan, block 0, single wave. Block-resolve: intra-block
    // suppression via one prefetched column word; keep rows OR'd into the
    // register-resident removed-mask with unconditional 16-load bundles.
    if (blockIdx.x != 0) return;
    if (tid < 64) {
        int lane = tid;
        u64 rem0 = 0, rem1 = 0;   // lane l holds removed words l, l+64
        int kept = 0;
        u64 colv = 0;
        if (lane < (int)nreal) colv = sup[(size_t)lane * NWORDS + 0];
        for (int w = 0; w < wreal; ++w) {
            u64 colnext = 0;
            int jn = (w + 1) * 64 + lane;
            if (w + 1 < wreal && jn < (int)nreal)
                colnext = sup[(size_t)jn * NWORDS + (w + 1)];

            int rembits = (int)nreal - w * 64;
            u64 vmw = (rembits >= 64) ? ~0ull : ((1ull << rembits) - 1ull);
            u64 remw = (w < 64) ? __shfl(rem0, w) : __shfl(rem1, w - 64);
            u64 live = vmw & ~remw;
            if (live) {
                u64 keeps_mask = 0;
                bool full = false;
                while (live) {
                    int b = __ffsll(live) - 1;
                    keeps_mask |= 1ull << b;
                    if (lane == 0) keepj[kept] = w * 64 + b;
                    kept++;
                    if (kept >= POST_N) { full = true; break; }
                    live &= ~(1ull << b);
                    live &= ~__shfl(colv, b);  // this block's bits suppressed by b
                }
                if (full) goto scandone;
                // cross-block: OR keep rows into rem. Unconditional 16-load
                // bundle (pad with first keep -> OR-idempotent), one wait.
                u64 km = keeps_mask;
                while (km) {
                    int bdef = __ffsll(km) - 1;
                    int bs[16];
#pragma unroll
                    for (int q = 0; q < 16; ++q) {
                        if (km) { bs[q] = __ffsll(km) - 1; km &= km - 1; }
                        else bs[q] = bdef;
                    }
                    if (lane < wreal) {
                        size_t rb = (size_t)(w * 64) * NWORDS + lane;
                        u64 acc = 0;
#pragma unroll
                        for (int q = 0; q < 16; ++q)
                            acc |= sup[rb + (size_t)bs[q] * NWORDS];
                        rem0 |= acc;
                    }
                    if (64 + lane < wreal) {   // only when >4096 candidates
                        size_t rb = (size_t)(w * 64) * NWORDS + 64 + lane;
                        u64 acc = 0;
#pragma unroll
                        for (int q = 0; q < 16; ++q)
                            acc |= sup[rb + (size_t)bs[q] * NWORDS];
                        rem1 |= acc;
                    }
                }
            }
            colv = colnext;
        }
scandone:
        if (lane == 0) s_kept = kept;
    }
    __syncthreads();
    // P6: parallel output gather + zero-fill (replaces d_out memset)
    {
        int kept = s_kept;
        for (int r = tid; r < POST_N; r += BT) {
            float4 v = make_float4(0.f, 0.f, 0.f, 0.f);
            if (r < kept) v = sP[keepj[r]];
            out[r] = v;
        }
    }
}

extern "C" void kernel_launch(void* const* d_in, const int* in_sizes, int n_in,
                              void* d_out, int out_size, void* d_ws, size_t ws_size,
                              hipStream_t stream) {
    const float* scores  = (const float*)d_in[0];
    const float* deltas  = (const float*)d_in[1];
    const float* anchors = (const float*)d_in[2];
    char* ws = (char*)d_ws;

    unsigned int* meta = (unsigned int*)(ws + OFF_META);
    u64*          cand = (u64*)(ws + OFF_CAND);
    float4*       cbox = (float4*)(ws + OFF_CBOX);
    u64*          key2 = (u64*)(ws + OFF_KEY2);
    float4*       boxA = (float4*)(ws + OFF_BOXA);
    float4*       sP   = (float4*)(ws + OFF_SP);
    float4*       sD   = (float4*)(ws + OFF_SD);
    u64*          sup  = (u64*)(ws + OFF_SUP);
    float4*       outp = (float4*)d_out;

    void* args[] = {
        (void*)&scores, (void*)&deltas, (void*)&anchors, (void*)&outp,
        (void*)&cand, (void*)&cbox, (void*)&key2, (void*)&boxA,
        (void*)&sP, (void*)&sD, (void*)&sup, (void*)&meta
    };
    hipLaunchCooperativeKernel((const void*)k_all, dim3(GRIDB), dim3(BT),
                               args, 0, stream);
}

// Round 8
// 146.292 us; speedup vs baseline: 1.8985x; 1.8985x over previous
//
#include <hip/hip_runtime.h>
#include <stdint.h>
#include <math.h>

#define NTOT (9*128*128)         // 147456
#define PRE_N 6000
#define POST_N 300
#define CAND_CAP 8192
#define NWORDS 94                // ceil(6000/64)
#define RT 256                   // rank-kernel threads
#define RTILE 2048               // rank-kernel LDS tile (keys, 16 KiB)

typedef unsigned long long u64;

// ---- ws layout (bytes) ----
constexpr size_t OFF_META = 0;                            // 64 B (meta[2]=cand counter)
constexpr size_t OFF_CAND = 64;                           // u64*CAND_CAP   = 65536
constexpr size_t OFF_CBOX = OFF_CAND + CAND_CAP*8;        // float4*CAND_CAP= 131072
constexpr size_t OFF_KEY2 = OFF_CBOX + CAND_CAP*16;       // u64*PRE_N      (pad 48128)
constexpr size_t OFF_BOXA = OFF_KEY2 + 48128;             // float4*PRE_N   (pad 96256)
constexpr size_t OFF_SP   = OFF_BOXA + 96256;             // float4*PRE_N
constexpr size_t OFF_SD   = OFF_SP + 96256;               // float4*PRE_N
constexpr size_t OFF_SUP  = OFF_SD + 96256;               // u64*PRE_N*NWORDS = 4512000

// monotone float -> uint (ascending order preserved, total order)
static __device__ __forceinline__ unsigned int ford(float f) {
    unsigned int b = __float_as_uint(f);
    return b ^ ((b & 0x80000000u) ? 0xFFFFFFFFu : 0x80000000u);
}

__global__ void k_boxes(const float* __restrict__ scores,
                        const float* __restrict__ deltas,
                        const float* __restrict__ anchors,
                        u64* __restrict__ cand,
                        float4* __restrict__ cbox,
                        unsigned int* __restrict__ cnt) {
    int i = blockIdx.x * blockDim.x + threadIdx.x;
    if (i >= NTOT) return;
    int a   = i >> 14;
    int rem = i & 16383;
    float4 d  = ((const float4*)deltas)[a * 16384 + rem]; // raw-reshape layout
    float4 an = ((const float4*)anchors)[i];
    float x1 = fmaxf(an.x + d.x, 0.0f);
    float y1 = fmaxf(an.y + d.y, 0.0f);
    float bw = fmaxf(an.z + d.z, 0.0f);
    float bh = fmaxf(an.w + d.w, 0.0f);
    float x2 = fminf(x1 + bw - 1.0f, 127.0f);   // uses pre-clamp x1
    float y2 = fminf(y1 + bh - 1.0f, 127.0f);
    x1 = fminf(x1, 127.0f);
    y1 = fminf(y1, 127.0f);
    bw = x2 - x1 + 1.0f;
    bh = y2 - y1 + 1.0f;
    bool valid = (bw >= 16.0f) && (bh >= 16.0f);
    // Only valid entries can ever reach the output (invalid score = -inf,
    // V=0 downstream). Append order is nondeterministic; ranks computed over
    // the unique keys make final placement deterministic.
    if (valid) {
        unsigned int inv = ~ford(scores[i]);    // ascending inv <=> score desc
        u64 key = ((u64)inv << 32) | (unsigned int)i;
        unsigned int p = atomicAdd(cnt, 1u);
        if (p < CAND_CAP) { cand[p] = key; cbox[p] = make_float4(x1, y1, bw, bh); }
    }
}

// rank by score-key (exact: keys unique). rank r = #{keys < mine}.
// r < PRE_N  =>  top-k slot r (score desc, idx asc = lax.top_k order).
__global__ void __launch_bounds__(RT)
k_rank1(const u64* __restrict__ cand, const float4* __restrict__ cbox,
        const unsigned int* __restrict__ meta,
        u64* __restrict__ key2, float4* __restrict__ boxA) {
    __shared__ u64 tile[RTILE];
    unsigned int cnt = meta[2];
    if (cnt > CAND_CAP) cnt = CAND_CAP;
    if ((unsigned)(blockIdx.x * RT) >= cnt) return;   // block-uniform skip
    int i = blockIdx.x * RT + threadIdx.x;
    bool act = (i < (int)cnt);
    u64 my = act ? cand[i] : ~0ull;
    int r = 0;
    for (unsigned int base = 0; base < cnt; base += RTILE) {
        unsigned int n = min((unsigned int)RTILE, cnt - base);
        for (unsigned int t = threadIdx.x; t < n; t += RT) tile[t] = cand[base + t];
        __syncthreads();
        if (act) {
            unsigned int t = 0;
            for (; t + 4 <= n; t += 4) {
                r += (tile[t]   < my);
                r += (tile[t+1] < my);
                r += (tile[t+2] < my);
                r += (tile[t+3] < my);
            }
            for (; t < n; ++t) r += (tile[t] < my);
        }
        __syncthreads();
    }
    if (act && r < PRE_N) {
        float4 b = cbox[i];
        float py2 = (b.y + b.w) - 1.0f;
        key2[r] = ((u64)(~ford(py2)) << 32) | (u64)r;   // (py2 desc, stable by rank)
        boxA[r] = b;
    }
}

// rank by py2-key among the top nreal; scatter boxes into final NMS order.
__global__ void __launch_bounds__(RT)
k_rank2(const u64* __restrict__ key2, const float4* __restrict__ boxA,
        const unsigned int* __restrict__ meta,
        float4* __restrict__ sP, float4* __restrict__ sD) {
    __shared__ u64 tile[RTILE];
    unsigned int cnt = meta[2];
    if (cnt > CAND_CAP) cnt = CAND_CAP;
    unsigned int nreal = (cnt < PRE_N) ? cnt : PRE_N;
    if ((unsigned)(blockIdx.x * RT) >= nreal) return;  // block-uniform skip
    int i = blockIdx.x * RT + threadIdx.x;    // i = top-k rank
    bool act = (i < (int)nreal);
    u64 my = act ? key2[i] : ~0ull;
    int r = 0;
    for (unsigned int base = 0; base < nreal; base += RTILE) {
        unsigned int n = min((unsigned int)RTILE, nreal - base);
        for (unsigned int t = threadIdx.x; t < n; t += RT) tile[t] = key2[base + t];
        __syncthreads();
        if (act) {
            unsigned int t = 0;
            for (; t + 4 <= n; t += 4) {
                r += (tile[t]   < my);
                r += (tile[t+1] < my);
                r += (tile[t+2] < my);
                r += (tile[t+3] < my);
            }
            for (; t < n; ++t) r += (tile[t] < my);
        }
        __syncthreads();
    }
    if (act) {
        float4 b = boxA[i];
        sP[r] = b;
        sD[r] = make_float4((b.x + b.z) - 1.0f, (b.y + b.w) - 1.0f,
                            b.z * b.w, 1.0f);
    }
}

__global__ void k_sup(const float4* __restrict__ sP,
                      const float4* __restrict__ sD,
                      const unsigned int* __restrict__ meta,
                      u64* __restrict__ sup) {
    unsigned int cnt = meta[2];
    if (cnt > CAND_CAP) cnt = CAND_CAP;
    int nreal = (cnt < PRE_N) ? (int)cnt : PRE_N;
    int wreal = (nreal + 63) >> 6;
    int t = blockIdx.x * blockDim.x + threadIdx.x;
    if (t >= PRE_N * NWORDS) return;
    int i = t % PRE_N;           // consecutive lanes -> consecutive i (coalesced)
    int w = t / PRE_N;
    if (i >= nreal || w >= wreal) return;   // never read downstream
    float4 p  = sP[i];
    float4 dI = sD[i];
    u64 bits = 0;
    int jbase = w * 64;
    int jend  = min(jbase + 64, nreal);
    for (int j = max(jbase, i + 1); j < jend; ++j) {
        float4 q  = sP[j];
        float4 dJ = sD[j];
        float iw = fmaxf(fminf(dI.x, dJ.x) - fmaxf(p.x, q.x) + 1.0f, 0.0f);
        float ih = fmaxf(fminf(dI.y, dJ.y) - fmaxf(p.y, q.y) + 1.0f, 0.0f);
        if (iw * ih >= 0.7f * dJ.z) bits |= 1ull << (j - jbase);
    }
    sup[(size_t)i * NWORDS + w] = bits;
}

// Per-KEEP serial scan (round-5 proven): removal state changes only on keeps
// (~300), so the dependent chain is keeps, not candidates. All nreal slots
// are valid by construction -> validity words computed from nreal.
__global__ void k_scan(const float4* __restrict__ sP,
                       const u64* __restrict__ sup,
                       const unsigned int* __restrict__ meta,
                       float4* __restrict__ out) {
    int lane = threadIdx.x;   // single wave of 64
    unsigned int cnt = meta[2];
    if (cnt > CAND_CAP) cnt = CAND_CAP;
    int nreal = (cnt < PRE_N) ? (int)cnt : PRE_N;
    int nblk = (nreal + 63) >> 6;
    u64 rem0 = 0, rem1 = 0;   // removed-mask: lane l holds words l, l+64
    int kept = 0;
    for (int w = 0; w < nblk; ++w) {
        int rembits = nreal - w * 64;
        u64 vmw = (rembits >= 64) ? ~0ull : ((1ull << rembits) - 1ull);
        u64 remw = (w < 64) ? __shfl(rem0, w) : __shfl(rem1, w - 64);
        u64 live = vmw & ~remw;
        while (live) {
            int b = __ffsll(live) - 1;
            int j = (w << 6) + b;
            if (lane == 0) out[kept] = sP[j];
            kept++;
            if (kept >= POST_N) goto done;
            // suppression row of the kept box (coalesced: lane l -> word l)
            u64 s0 = (lane < nblk)      ? sup[(size_t)j * NWORDS + lane]      : 0ull;
            u64 s1 = (64 + lane < nblk) ? sup[(size_t)j * NWORDS + 64 + lane] : 0ull;
            rem0 |= s0;
            rem1 |= s1;
            u64 sw = (w < 64) ? __shfl(s0, w) : __shfl(s1, w - 64);
            live &= ~(1ull << b);   // row never has its own bit (strict i<j)
            live &= ~sw;
        }
    }
done:
    // zero-fill remaining output rows (replaces a d_out memset dispatch)
    for (int r = kept + lane; r < POST_N; r += 64)
        out[r] = make_float4(0.f, 0.f, 0.f, 0.f);
}

extern "C" void kernel_launch(void* const* d_in, const int* in_sizes, int n_in,
                              void* d_out, int out_size, void* d_ws, size_t ws_size,
                              hipStream_t stream) {
    const float* scores  = (const float*)d_in[0];
    const float* deltas  = (const float*)d_in[1];
    const float* anchors = (const float*)d_in[2];
    char* ws = (char*)d_ws;

    unsigned int* meta = (unsigned int*)(ws + OFF_META);
    u64*          cand = (u64*)(ws + OFF_CAND);
    float4*       cbox = (float4*)(ws + OFF_CBOX);
    u64*          key2 = (u64*)(ws + OFF_KEY2);
    float4*       boxA = (float4*)(ws + OFF_BOXA);
    float4*       sP   = (float4*)(ws + OFF_SP);
    float4*       sD   = (float4*)(ws + OFF_SD);
    u64*          sup  = (u64*)(ws + OFF_SUP);

    hipMemsetAsync(ws + OFF_META, 0, 64, stream);   // zero cand counter

    k_boxes<<<(NTOT + 255) / 256, 256, 0, stream>>>(scores, deltas, anchors,
                                                    cand, cbox, &meta[2]);
    k_rank1<<<CAND_CAP / RT, RT, 0, stream>>>(cand, cbox, meta, key2, boxA);
    k_rank2<<<(PRE_N + RT - 1) / RT, RT, 0, stream>>>(key2, boxA, meta, sP, sD);
    k_sup<<<(PRE_N * NWORDS + 255) / 256, 256, 0, stream>>>(sP, sD, meta, sup);
    k_scan<<<1, 64, 0, stream>>>(sP, sup, meta, (float4*)d_out);
}

// Round 9
// 142.963 us; speedup vs baseline: 1.9427x; 1.0233x over previous
//
#include <hip/hip_runtime.h>
#include <stdint.h>
#include <math.h>

#define NTOT (9*128*128)         // 147456
#define PRE_N 6000
#define POST_N 300
#define CAND_CAP 8192
#define NWORDS 94                // ceil(6000/64)
#define RT 256                   // rank-kernel threads
#define RTILE 2048               // rank-kernel LDS tile (keys, 16 KiB)
#define NMS_T 1024

typedef unsigned long long u64;

// ---- ws layout (bytes) ----
constexpr size_t OFF_META = 0;                            // 64 B (meta[2]=cand counter)
constexpr size_t OFF_CAND = 64;                           // u64*CAND_CAP   = 65536
constexpr size_t OFF_CBOX = OFF_CAND + CAND_CAP*8;        // float4*CAND_CAP= 131072
constexpr size_t OFF_KEY2 = OFF_CBOX + CAND_CAP*16;       // u64*PRE_N      (pad 48128)
constexpr size_t OFF_BOXA = OFF_KEY2 + 48128;             // float4*PRE_N   (pad 96256)
constexpr size_t OFF_SP   = OFF_BOXA + 96256;             // float4*PRE_N
constexpr size_t OFF_SD   = OFF_SP + 96256;               // float4*PRE_N

// monotone float -> uint (ascending order preserved, total order)
static __device__ __forceinline__ unsigned int ford(float f) {
    unsigned int b = __float_as_uint(f);
    return b ^ ((b & 0x80000000u) ? 0xFFFFFFFFu : 0x80000000u);
}

__global__ void k_boxes(const float* __restrict__ scores,
                        const float* __restrict__ deltas,
                        const float* __restrict__ anchors,
                        u64* __restrict__ cand,
                        float4* __restrict__ cbox,
                        unsigned int* __restrict__ cnt) {
    int i = blockIdx.x * blockDim.x + threadIdx.x;
    if (i >= NTOT) return;
    int a   = i >> 14;
    int rem = i & 16383;
    float4 d  = ((const float4*)deltas)[a * 16384 + rem]; // raw-reshape layout
    float4 an = ((const float4*)anchors)[i];
    float x1 = fmaxf(an.x + d.x, 0.0f);
    float y1 = fmaxf(an.y + d.y, 0.0f);
    float bw = fmaxf(an.z + d.z, 0.0f);
    float bh = fmaxf(an.w + d.w, 0.0f);
    float x2 = fminf(x1 + bw - 1.0f, 127.0f);   // uses pre-clamp x1
    float y2 = fminf(y1 + bh - 1.0f, 127.0f);
    x1 = fminf(x1, 127.0f);
    y1 = fminf(y1, 127.0f);
    bw = x2 - x1 + 1.0f;
    bh = y2 - y1 + 1.0f;
    bool valid = (bw >= 16.0f) && (bh >= 16.0f);
    // Only valid entries can ever reach the output (invalid score = -inf,
    // V=0 downstream). Append order is nondeterministic; ranks computed over
    // the unique keys make final placement deterministic.
    if (valid) {
        unsigned int inv = ~ford(scores[i]);    // ascending inv <=> score desc
        u64 key = ((u64)inv << 32) | (unsigned int)i;
        unsigned int p = atomicAdd(cnt, 1u);
        if (p < CAND_CAP) { cand[p] = key; cbox[p] = make_float4(x1, y1, bw, bh); }
    }
}

// rank by score-key (exact: keys unique). rank r = #{keys < mine}.
// r < PRE_N  =>  top-k slot r (score desc, idx asc = lax.top_k order).
__global__ void __launch_bounds__(RT)
k_rank1(const u64* __restrict__ cand, const float4* __restrict__ cbox,
        const unsigned int* __restrict__ meta,
        u64* __restrict__ key2, float4* __restrict__ boxA) {
    __shared__ u64 tile[RTILE];
    unsigned int cnt = meta[2];
    if (cnt > CAND_CAP) cnt = CAND_CAP;
    if ((unsigned)(blockIdx.x * RT) >= cnt) return;   // block-uniform skip
    int i = blockIdx.x * RT + threadIdx.x;
    bool act = (i < (int)cnt);
    u64 my = act ? cand[i] : ~0ull;
    int r = 0;
    for (unsigned int base = 0; base < cnt; base += RTILE) {
        unsigned int n = min((unsigned int)RTILE, cnt - base);
        for (unsigned int t = threadIdx.x; t < n; t += RT) tile[t] = cand[base + t];
        __syncthreads();
        if (act) {
            unsigned int t = 0;
            for (; t + 4 <= n; t += 4) {
                r += (tile[t]   < my);
                r += (tile[t+1] < my);
                r += (tile[t+2] < my);
                r += (tile[t+3] < my);
            }
            for (; t < n; ++t) r += (tile[t] < my);
        }
        __syncthreads();
    }
    if (act && r < PRE_N) {
        float4 b = cbox[i];
        float py2 = (b.y + b.w) - 1.0f;
        key2[r] = ((u64)(~ford(py2)) << 32) | (u64)r;   // (py2 desc, stable by rank)
        boxA[r] = b;
    }
}

// rank by py2-key among the top nreal; scatter boxes into final NMS order.
__global__ void __launch_bounds__(RT)
k_rank2(const u64* __restrict__ key2, const float4* __restrict__ boxA,
        const unsigned int* __restrict__ meta,
        float4* __restrict__ sP, float4* __restrict__ sD) {
    __shared__ u64 tile[RTILE];
    unsigned int cnt = meta[2];
    if (cnt > CAND_CAP) cnt = CAND_CAP;
    unsigned int nreal = (cnt < PRE_N) ? cnt : PRE_N;
    if ((unsigned)(blockIdx.x * RT) >= nreal) return;  // block-uniform skip
    int i = blockIdx.x * RT + threadIdx.x;    // i = top-k rank
    bool act = (i < (int)nreal);
    u64 my = act ? key2[i] : ~0ull;
    int r = 0;
    for (unsigned int base = 0; base < nreal; base += RTILE) {
        unsigned int n = min((unsigned int)RTILE, nreal - base);
        for (unsigned int t = threadIdx.x; t < n; t += RT) tile[t] = key2[base + t];
        __syncthreads();
        if (act) {
            unsigned int t = 0;
            for (; t + 4 <= n; t += 4) {
                r += (tile[t]   < my);
                r += (tile[t+1] < my);
                r += (tile[t+2] < my);
                r += (tile[t+3] < my);
            }
            for (; t < n; ++t) r += (tile[t] < my);
        }
        __syncthreads();
    }
    if (act) {
        float4 b = boxA[i];
        sP[r] = b;
        sD[r] = make_float4((b.x + b.z) - 1.0f, (b.y + b.w) - 1.0f,
                            b.z * b.w, 1.0f);
    }
}

// Single-block greedy NMS entirely from LDS: per 64-candidate block, wave 0
// resolves intra-block keeps in registers (shfl + ballot, no memory in the
// serial chain); then all 16 waves suppress later candidates in parallel.
__global__ void __launch_bounds__(NMS_T)
k_nms(const float4* __restrict__ sP, const float4* __restrict__ sD,
      const unsigned int* __restrict__ meta, float4* __restrict__ out) {
    __shared__ float bx1[PRE_N], by1[PRE_N], bx2[PRE_N], by2[PRE_N], bar[PRE_N];
    __shared__ unsigned int rem32[2 * NWORDS];   // removed bitmap (188 words)
    __shared__ int keepj[POST_N];
    __shared__ int s_keeps[64];
    __shared__ int s_nk, s_stop, s_kept;

    int tid = threadIdx.x;
    unsigned int cnt = meta[2];
    if (cnt > CAND_CAP) cnt = CAND_CAP;
    int nreal = (cnt < PRE_N) ? (int)cnt : PRE_N;
    int nblk = (nreal + 63) >> 6;

    for (int c = tid; c < nreal; c += NMS_T) {
        float4 p = sP[c]; float4 d = sD[c];
        bx1[c] = p.x; by1[c] = p.y; bx2[c] = d.x; by2[c] = d.y; bar[c] = d.z;
    }
    for (int i = tid; i < 2 * NWORDS; i += NMS_T) rem32[i] = 0;
    if (tid == 0) { s_kept = 0; s_stop = 0; }
    __syncthreads();

    for (int w = 0; w < nblk; ++w) {
        if (tid < 64) {                       // wave 0: resolve block w
            int lane = tid;
            int c = (w << 6) + lane;
            bool has = (c < nreal);
            float cx1 = 0, cy1 = 0, cx2 = 0, cy2 = 0, car = 0;
            if (has) { cx1 = bx1[c]; cy1 = by1[c]; cx2 = bx2[c]; cy2 = by2[c]; car = bar[c]; }
            u64 rw = ((u64)rem32[2 * w]) | (((u64)rem32[2 * w + 1]) << 32);
            int rembits = nreal - (w << 6);
            u64 vm = (rembits >= 64) ? ~0ull : ((1ull << rembits) - 1ull);
            u64 live = vm & ~rw;
            int kept = s_kept;
            int nk = 0;
            while (live) {
                int b = __ffsll(live) - 1;
                if (lane == 0) { keepj[kept] = (w << 6) + b; s_keeps[nk] = (w << 6) + b; }
                nk++; kept++;
                if (kept >= POST_N) { if (lane == 0) s_stop = 1; break; }
                live &= ~(1ull << b);
                // suppression of this block's later live lanes by keep b
                float jx1 = __shfl(cx1, b), jy1 = __shfl(cy1, b);
                float jx2 = __shfl(cx2, b), jy2 = __shfl(cy2, b);
                float iw = fmaxf(fminf(jx2, cx2) - fmaxf(jx1, cx1) + 1.0f, 0.0f);
                float ih = fmaxf(fminf(jy2, cy2) - fmaxf(jy1, cy1) + 1.0f, 0.0f);
                bool sup = has && (lane > b) && (iw * ih >= 0.7f * car);
                live &= ~__ballot(sup);
            }
            if (lane == 0) { s_nk = nk; s_kept = kept; }
        }
        __syncthreads();
        if (s_stop) break;                    // uniform
        int nk = s_nk;
        if (nk > 0) {
            // all waves: suppress candidates in blocks > w
            for (int c = ((w + 1) << 6) + tid; c < nreal; c += NMS_T) {
                unsigned int wbit = 1u << (c & 31);
                unsigned int* wp = &rem32[c >> 5];
                if (*wp & wbit) continue;     // already removed (stale-ok)
                float cx1 = bx1[c], cy1 = by1[c], cx2 = bx2[c], cy2 = by2[c], car = bar[c];
                bool supp = false;
                for (int q = 0; q < nk; ++q) {
                    int j = s_keeps[q];
                    float iw = fmaxf(fminf(bx2[j], cx2) - fmaxf(bx1[j], cx1) + 1.0f, 0.0f);
                    float ih = fmaxf(fminf(by2[j], cy2) - fmaxf(by1[j], cy1) + 1.0f, 0.0f);
                    if (iw * ih >= 0.7f * car) { supp = true; break; }
                }
                if (supp) atomicOr(wp, wbit);
            }
        }
        __syncthreads();                      // rem32 visible to next resolve
    }

    __syncthreads();
    int fk = s_kept;
    for (int r = tid; r < POST_N; r += NMS_T) {
        float4 v = make_float4(0.f, 0.f, 0.f, 0.f);
        if (r < fk) v = sP[keepj[r]];
        out[r] = v;
    }
}

extern "C" void kernel_launch(void* const* d_in, const int* in_sizes, int n_in,
                              void* d_out, int out_size, void* d_ws, size_t ws_size,
                              hipStream_t stream) {
    const float* scores  = (const float*)d_in[0];
    const float* deltas  = (const float*)d_in[1];
    const float* anchors = (const float*)d_in[2];
    char* ws = (char*)d_ws;

    unsigned int* meta = (unsigned int*)(ws + OFF_META);
    u64*          cand = (u64*)(ws + OFF_CAND);
    float4*       cbox = (float4*)(ws + OFF_CBOX);
    u64*          key2 = (u64*)(ws + OFF_KEY2);
    float4*       boxA = (float4*)(ws + OFF_BOXA);
    float4*       sP   = (float4*)(ws + OFF_SP);
    float4*       sD   = (float4*)(ws + OFF_SD);

    hipMemsetAsync(ws + OFF_META, 0, 64, stream);   // zero cand counter

    k_boxes<<<(NTOT + 255) / 256, 256, 0, stream>>>(scores, deltas, anchors,
                                                    cand, cbox, &meta[2]);
    k_rank1<<<CAND_CAP / RT, RT, 0, stream>>>(cand, cbox, meta, key2, boxA);
    k_rank2<<<(PRE_N + RT - 1) / RT, RT, 0, stream>>>(key2, boxA, meta, sP, sD);
    k_nms<<<1, NMS_T, 0, stream>>>(sP, sD, meta, (float4*)d_out);
}